// Round 16
// baseline (177.416 us; speedup 1.0000x reference)
//
#include <hip/hip_runtime.h>
#include <hip/hip_bf16.h>

// Problem constants
#define B_   16
#define N_   1024
#define C_   768
#define H_   12
#define HD_  64
#define M_   16384   // B*N tokens
#define N1_  2304    // 3*C
#define NEG_BIG (-1e30f)
#define LOG2E 1.4426950408889634f

typedef __attribute__((ext_vector_type(8))) _Float16 f16x8;  // 8 fp16 = 4 VGPR
typedef __attribute__((ext_vector_type(4))) float f32x4;
typedef __attribute__((ext_vector_type(16))) float f32x16;

// ---- fp16 helpers ----
__device__ __forceinline__ unsigned short f2h(float f) {   // RNE
  _Float16 h = (_Float16)f;
  union { _Float16 h; unsigned short u; } c; c.h = h; return c.u;
}
__device__ __forceinline__ unsigned int cvtpk_f16(float a, float b) {  // RTZ pack
  unsigned int r;
  asm("v_cvt_pkrtz_f16_f32 %0, %1, %2" : "=v"(r) : "v"(a), "v"(b));
  return r;
}
__device__ __forceinline__ float exp2_asm(float x) {
  float r;
  asm("v_exp_f32 %0, %1" : "=v"(r) : "v"(x));
  return r;
}

__device__ __forceinline__ void gload_lds16(const void* g, void* l) {
  __builtin_amdgcn_global_load_lds(
      (const __attribute__((address_space(1))) void*)g,
      (__attribute__((address_space(3))) void*)l, 16, 0, 0);
}

typedef __attribute__((ext_vector_type(8))) short u16x8;

// =====================================================================
// Fused prep: blocks [0,6144) cvt x; [6144,7008) WqkvT; [7008,7296) WoutT
// =====================================================================
__global__ __launch_bounds__(256)
void k_prep_all(const float* __restrict__ x, const float* __restrict__ Wqkv,
                const float* __restrict__ Wout,
                unsigned short* __restrict__ xh,
                unsigned short* __restrict__ WqkvT,
                unsigned short* __restrict__ WoutT) {
  int bid = blockIdx.x;
  if (bid < 6144) {
    long i = ((long)bid * 256 + threadIdx.x) * 8;
    float4 a = *(const float4*)(x + i);
    float4 b = *(const float4*)(x + i + 4);
    u16x8 v;
    v[0] = (short)f2h(a.x); v[1] = (short)f2h(a.y);
    v[2] = (short)f2h(a.z); v[3] = (short)f2h(a.w);
    v[4] = (short)f2h(b.x); v[5] = (short)f2h(b.y);
    v[6] = (short)f2h(b.z); v[7] = (short)f2h(b.w);
    *(u16x8*)(xh + i) = v;
  } else if (bid < 7008) {
    int tid = (bid - 6144) * 256 + threadIdx.x;   // 96*2304 threads
    int n  = tid % N1_;
    int kc = tid / N1_;                            // 0..95
    u16x8 v;
#pragma unroll
    for (int j = 0; j < 8; ++j)
      v[j] = (short)f2h(Wqkv[(long)(kc * 8 + j) * N1_ + n]);
    *(u16x8*)(WqkvT + (long)n * C_ + kc * 8) = v;
  } else {
    int tid = (bid - 7008) * 256 + threadIdx.x;   // 96*768 threads
    int n  = tid % C_;
    int kc = tid / C_;                             // 0..95
    u16x8 v;
#pragma unroll
    for (int j = 0; j < 8; ++j)
      v[j] = (short)f2h(Wout[(long)(kc * 8 + j) * C_ + n]);
    *(u16x8*)(WoutT + (long)n * C_ + kc * 8) = v;
  }
}

// =====================================================================
// 128x128 GEMM (m97 2-barrier structure, fp16): C = A * Bt^T + bias
// STAGE 1: fp16 out. Q/K col-blocks -> qkvb; V col-blocks (n0>=1536)
// transposed directly into Vt [bh][64 d][1024 n]. STAGE 3: fp32 direct.
// =====================================================================
template <int STAGE>
__global__ __launch_bounds__(256, 4)
void gemm128(const unsigned short* __restrict__ A,
             const unsigned short* __restrict__ Bt,
             const float* __restrict__ bias,
             void* __restrict__ out, unsigned short* __restrict__ Vt,
             int Kdim, int Ndim) {
  __shared__ unsigned char lds[32768];   // A tile 16K | B tile 16K
  const int t = threadIdx.x;
  const int l = t & 63, w = t >> 6;
  const int g = l >> 4, lr = l & 15;
  const int NB = Ndim >> 7;
  const int wgid = (blockIdx.x & 7) * (gridDim.x >> 3) + (blockIdx.x >> 3);
  const int mb = wgid / NB, nb = wgid % NB;
  const long m0 = (long)mb << 7, n0 = (long)nb << 7;
  const int wm = w >> 1, wn = w & 1;

  f32x4 acc[4][4];
  const f32x4 zz = {0.f, 0.f, 0.f, 0.f};
#pragma unroll
  for (int i = 0; i < 4; ++i)
#pragma unroll
    for (int j = 0; j < 4; ++j) acc[i][j] = zz;

  int srow[4], sx[4];
#pragma unroll
  for (int i = 0; i < 4; ++i) {
    int s = i * 4096 + t * 16;
    int row = s >> 7;
    srow[i] = row;
    sx[i] = (s & 127) ^ ((row & 7) << 4);
  }
  const char* Ab = (const char*)A;
  const char* Bb = (const char*)Bt;
  const long K2 = (long)Kdim * 2;
  const int wbase = (t & 192) * 16;   // wave-uniform LDS base (w*1024)

  for (int kt = 0; kt < Kdim; kt += 64) {
#pragma unroll
    for (int i = 0; i < 4; ++i) {
      const char* src = Ab + (m0 + srow[i]) * K2 + kt * 2 + sx[i];
      gload_lds16(src, (void*)(lds + i * 4096 + wbase));
    }
#pragma unroll
    for (int i = 0; i < 4; ++i) {
      const char* src = Bb + (n0 + srow[i]) * K2 + kt * 2 + sx[i];
      gload_lds16(src, (void*)(lds + 16384 + i * 4096 + wbase));
    }
    __syncthreads();
#pragma unroll
    for (int ks = 0; ks < 2; ++ks) {
      f16x8 af[4], bfr[4];
#pragma unroll
      for (int mi = 0; mi < 4; ++mi) {
        int row = wm * 64 + mi * 16 + lr;
        int off = row * 128 + ((ks * 64 + g * 16) ^ ((row & 7) << 4));
        af[mi] = *(const f16x8*)(lds + off);
      }
#pragma unroll
      for (int ni = 0; ni < 4; ++ni) {
        int row = wn * 64 + ni * 16 + lr;
        int off = 16384 + row * 128 + ((ks * 64 + g * 16) ^ ((row & 7) << 4));
        bfr[ni] = *(const f16x8*)(lds + off);
      }
#pragma unroll
      for (int mi = 0; mi < 4; ++mi)
#pragma unroll
        for (int ni = 0; ni < 4; ++ni)
          acc[mi][ni] = __builtin_amdgcn_mfma_f32_16x16x32_f16(
              af[mi], bfr[ni], acc[mi][ni], 0, 0, 0);
    }
    __syncthreads();
  }

  // ---- epilogue ----
  if (STAGE == 1 && n0 >= 1536) {
    // V path: stage C-tile COL-MAJOR (lt[col][row^s]) then write Vt rows
    unsigned short* lt = (unsigned short*)lds;
#pragma unroll
    for (int ni = 0; ni < 4; ++ni) {
      int col = wn * 64 + ni * 16 + lr;
      int s = (col & 15) << 3;
      float bv = bias[(int)n0 + col];
#pragma unroll
      for (int mi = 0; mi < 4; ++mi) {
        int rowb = wm * 64 + mi * 16 + g * 4;
        unsigned d0 = cvtpk_f16(acc[mi][ni][0] + bv, acc[mi][ni][1] + bv);
        unsigned d1 = cvtpk_f16(acc[mi][ni][2] + bv, acc[mi][ni][3] + bv);
        unsigned long long dd = (unsigned long long)d0 |
                                ((unsigned long long)d1 << 32);
        *(unsigned long long*)(lt + col * 128 + (rowb ^ s)) = dd;
      }
    }
    __syncthreads();
    const int b_  = (int)(m0 >> 10);
    const int nof = (int)(m0 & 1023);
    const int h0  = ((int)n0 - 1536) >> 6;
#pragma unroll
    for (int it = 0; it < 8; ++it) {
      int col  = it * 16 + (t >> 4);
      int tokc = (t & 15) * 8;
      int s = (col & 15) << 3;
      u16x8 v = *(const u16x8*)(lt + col * 128 + (tokc ^ s));
      int bh = b_ * H_ + h0 + (col >> 6);
      int d  = col & 63;
      *(u16x8*)(Vt + ((long)bh * HD_ + d) * N_ + nof + tokc) = v;
    }
  } else if (STAGE == 1) {
    float sc = (n0 < 768) ? 0.125f * LOG2E : 1.0f;  // Q pre-scale (exp2 dom)
    unsigned short* cl = (unsigned short*)lds;
#pragma unroll
    for (int ni = 0; ni < 4; ++ni) {
      int col = wn * 64 + ni * 16 + lr;
      float bv = bias[(int)n0 + col];
#pragma unroll
      for (int mi = 0; mi < 4; ++mi)
#pragma unroll
        for (int r = 0; r < 4; ++r) {
          int row = wm * 64 + mi * 16 + g * 4 + r;
          cl[row * 128 + col] = f2h((acc[mi][ni][r] + bv) * sc);
        }
    }
    __syncthreads();
    unsigned short* o = (unsigned short*)out;
#pragma unroll
    for (int it = 0; it < 8; ++it) {
      int idx = it * 2048 + t * 8;         // shorts
      int row = idx >> 7;
      int col = idx & 127;
      *(u16x8*)(o + (m0 + row) * N1_ + n0 + col) = *(const u16x8*)(cl + idx);
    }
  } else {
    float* o = (float*)out;
#pragma unroll
    for (int ni = 0; ni < 4; ++ni) {
      int col = (int)n0 + wn * 64 + ni * 16 + lr;
      float bv = bias[col];
#pragma unroll
      for (int mi = 0; mi < 4; ++mi)
#pragma unroll
        for (int r = 0; r < 4; ++r) {
          long rowm = m0 + wm * 64 + mi * 16 + g * 4 + r;
          o[rowm * C_ + col] = acc[mi][ni][r] + bv;
        }
    }
  }
}

// =====================================================================
// Fused flash attention, 32x32x16 fp16 MFMA, fully-transposed form.
// r14 structure (tri-buffered K/V, 1 barrier/tile, proven correct) plus
// ONLY s_setprio(1) around the two MFMA clusters (T5 — scheduler hint,
// correctness-neutral). r15's rotation + permlane-reduce are reverted.
// 512 threads / 8 waves / 256 q per block; grid 768 = 3 blocks/CU.
// =====================================================================
__global__ __launch_bounds__(512, 2)
void attn_fused(const unsigned short* __restrict__ qkvb,
                const unsigned short* __restrict__ Vt,
                unsigned short* __restrict__ Ofp) {
  __shared__ unsigned char lds[49152];  // 3 x (K 8K | V 8K)
  const int t = threadIdx.x, l = t & 63, w = t >> 6;   // 8 waves
  const int q32 = l & 31;
  const int hi = l >> 5;
  const int hi16 = hi * 16;
  const int wid = (blockIdx.x & 7) * 96 + (blockIdx.x >> 3);  // XCD-chunked
  const int bh = wid >> 2, qb = wid & 3;
  const int b = bh / H_, h = bh % H_;
  const long tok0 = (long)b * N_;
  const int q0 = qb * 256 + w * 32;
  const long mytok = tok0 + q0 + q32;

  // Q B-fragments (pre-scaled by 0.125*log2e in stage-1)
  f16x8 qa[4];
#pragma unroll
  for (int cs = 0; cs < 4; ++cs)
    qa[cs] = *(const f16x8*)(qkvb + mytok * N1_ + h * HD_ + cs * 16 + hi * 8);

  const f32x16 zz16 = {0.f};
  f32x16 o0 = zz16, o1 = zz16;   // O^T: d 0..31 / 32..63 for lane's q
  float mrun = NEG_BIG, lrun = 0.f;

  const int row0 = q32, row1 = 32 + q32;
  const int swz0 = (q32 & 7) << 4;    // period-8 / 16B XOR

  // staging: 512 threads cover one 16KB K/V tile pair per issue;
  // row = t>>3 (0..63), col = (t&7)*16, source pre-swizzled
  const int srowk = t >> 3;
  const int sxs = ((t & 7) * 16) ^ (((t >> 3) & 7) << 4);
  const int wbase = (t & 448) * 16;   // w * 1024
  const char* Vg = (const char*)(Vt + (long)bh * HD_ * N_);
  const char* Kg = (const char*)qkvb + ((tok0)*N1_ + C_ + h * HD_) * 2;

#define STAGE_KV(kv0, buf)                                                  \
  {                                                                         \
    gload_lds16(Kg + ((long)((kv0) + srowk) * N1_) * 2 + sxs,               \
                (void*)((buf) + wbase));                                    \
    gload_lds16(Vg + ((long)srowk * N_ + (kv0)) * 2 + sxs,                  \
                (void*)((buf) + 8192 + wbase));                             \
  }

  STAGE_KV(0, lds);            // tile 0 -> buf 0
  STAGE_KV(64, lds + 16384);   // tile 1 -> buf 1

  int cur = 0, nx2 = 2;        // rolling buffer indices: tt%3, (tt+2)%3
  for (int tt = 0; tt < 16; ++tt) {
    unsigned char* curb = lds + cur * 16384;
    if (tt < 15) {
      asm volatile("s_waitcnt vmcnt(2)" ::: "memory");   // tile-tt data landed
    } else {
      asm volatile("s_waitcnt vmcnt(0)" ::: "memory");
    }
    __builtin_amdgcn_s_barrier();          // all waves now inside tile tt
    __builtin_amdgcn_sched_barrier(0);
    if (tt + 2 < 16) {
      STAGE_KV((tt + 2) * 64, lds + nx2 * 16384);  // hides under compute
    }

    // ---- S^T = mfma(K_A, Q_B) ----
    f32x16 sa0 = zz16, sa1 = zz16;
    __builtin_amdgcn_s_setprio(1);
#pragma unroll
    for (int cs = 0; cs < 4; ++cs) {
      f16x8 kf0 = *(const f16x8*)(curb + row0 * 128 + ((cs * 32 + hi16) ^ swz0));
      f16x8 kf1 = *(const f16x8*)(curb + row1 * 128 + ((cs * 32 + hi16) ^ swz0));
      sa0 = __builtin_amdgcn_mfma_f32_32x32x16_f16(kf0, qa[cs], sa0, 0, 0, 0);
      sa1 = __builtin_amdgcn_mfma_f32_32x32x16_f16(kf1, qa[cs], sa1, 0, 0, 0);
    }
    __builtin_amdgcn_s_setprio(0);

    // ---- in-lane online softmax (log2 domain), max3-fused tree ----
    float tm[11];
#pragma unroll
    for (int i = 0; i < 5; ++i)
      tm[i] = fmaxf(fmaxf(sa0[3 * i], sa0[3 * i + 1]), sa0[3 * i + 2]);
    tm[5] = fmaxf(sa0[15], sa1[0]);
#pragma unroll
    for (int i = 0; i < 5; ++i)
      tm[6 + i] = fmaxf(fmaxf(sa1[3 * i + 1], sa1[3 * i + 2]), sa1[3 * i + 3]);
    float u0 = fmaxf(fmaxf(tm[0], tm[1]), tm[2]);
    float u1 = fmaxf(fmaxf(tm[3], tm[4]), tm[5]);
    float u2 = fmaxf(fmaxf(tm[6], tm[7]), tm[8]);
    float u3 = fmaxf(fmaxf(tm[9], tm[10]), u0);
    float mx = fmaxf(fmaxf(u1, u2), u3);
    mx = fmaxf(mx, __shfl_xor(mx, 32));
    if (!__all(mx <= mrun + 8.f)) {           // defer-max: P <= 2^8
      float mn = fmaxf(mrun, mx);
      float al = exp2_asm(mrun - mn);
      mrun = mn;
      lrun *= al;
      o0 *= al;
      o1 *= al;
    }
    float p0a[16], p1a[16];
#pragma unroll
    for (int i = 0; i < 16; ++i) p0a[i] = exp2_asm(sa0[i] - mrun);
#pragma unroll
    for (int i = 0; i < 16; ++i) p1a[i] = exp2_asm(sa1[i] - mrun);
    unsigned pk[2][4][2];
#pragma unroll
    for (int g = 0; g < 4; ++g) {
      pk[0][g][0] = cvtpk_f16(p0a[4 * g + 0], p0a[4 * g + 1]);
      pk[0][g][1] = cvtpk_f16(p0a[4 * g + 2], p0a[4 * g + 3]);
      pk[1][g][0] = cvtpk_f16(p1a[4 * g + 0], p1a[4 * g + 1]);
      pk[1][g][1] = cvtpk_f16(p1a[4 * g + 2], p1a[4 * g + 3]);
    }
    float ts[16];
#pragma unroll
    for (int i = 0; i < 16; ++i) ts[i] = p0a[i] + p1a[i];
#pragma unroll
    for (int s = 8; s >= 1; s >>= 1)
#pragma unroll
      for (int i = 0; i < s; ++i) ts[i] += ts[i + s];
    float rs = ts[0];
    rs += __shfl_xor(rs, 32);
    lrun += rs;

    // ---- P^T -> B-operand fragments via permlane32_swap ----
    f16x8 pb[4];
#pragma unroll
    for (int tk = 0; tk < 2; ++tk)
#pragma unroll
      for (int par = 0; par < 2; ++par) {
        unsigned a0 = pk[tk][2 * par][0], b0 = pk[tk][2 * par + 1][0];
        unsigned a1 = pk[tk][2 * par][1], b1 = pk[tk][2 * par + 1][1];
        asm("v_permlane32_swap_b32 %0, %1" : "+v"(a0), "+v"(b0));
        asm("v_permlane32_swap_b32 %0, %1" : "+v"(a1), "+v"(b1));
        union { unsigned u[4]; f16x8 v; } pw;
        pw.u[0] = a0; pw.u[1] = a1; pw.u[2] = b0; pw.u[3] = b1;
        pb[2 * tk + par] = pw.v;
      }

    // ---- O^T += mfma(V^T_A, P_B) ----
    __builtin_amdgcn_s_setprio(1);
#pragma unroll
    for (int kb = 0; kb < 4; ++kb) {
      f16x8 vf0 = *(const f16x8*)(curb + 8192 + row0 * 128 + ((kb * 32 + hi16) ^ swz0));
      f16x8 vf1 = *(const f16x8*)(curb + 8192 + row1 * 128 + ((kb * 32 + hi16) ^ swz0));
      o0 = __builtin_amdgcn_mfma_f32_32x32x16_f16(vf0, pb[kb], o0, 0, 0, 0);
      o1 = __builtin_amdgcn_mfma_f32_32x32x16_f16(vf1, pb[kb], o1, 0, 0, 0);
    }
    __builtin_amdgcn_s_setprio(0);
    // rotate buffer indices (no second barrier: tri-buffer makes it safe)
    cur = (cur == 2) ? 0 : cur + 1;
    nx2 = (nx2 == 2) ? 0 : nx2 + 1;
  }
#undef STAGE_KV

  // ---- epilogue: normalize, fp16 pack, merged 8B stores ----
  float inv = 1.0f / lrun;
  unsigned short* obase = Ofp + mytok * C_ + h * HD_;
#pragma unroll
  for (int dt = 0; dt < 2; ++dt) {
#pragma unroll
    for (int j = 0; j < 4; ++j) {
      int r = 4 * j;
      const f32x16& oo = dt ? o1 : o0;
      unsigned hw0 = cvtpk_f16(oo[r] * inv, oo[r + 1] * inv);
      unsigned hw1 = cvtpk_f16(oo[r + 2] * inv, oo[r + 3] * inv);
      unsigned long long dd = (unsigned long long)hw0 |
                              ((unsigned long long)hw1 << 32);
      int d = dt * 32 + 8 * j + 4 * hi;
      *(unsigned long long*)(obase + d) = dd;
    }
  }
}

// =====================================================================
extern "C" void kernel_launch(void* const* d_in, const int* in_sizes, int n_in,
                              void* d_out, int out_size, void* d_ws, size_t ws_size,
                              hipStream_t stream) {
  const float* x    = (const float*)d_in[0];
  const float* Wqkv = (const float*)d_in[1];
  const float* bqkv = (const float*)d_in[2];
  const float* Wout = (const float*)d_in[3];
  const float* bout = (const float*)d_in[4];

  char* ws = (char*)d_ws;
  unsigned short* qkvb  = (unsigned short*)(ws);                 // 75,497,472 B
  unsigned short* Ofp   = (unsigned short*)(ws + 75497472L);     // 25,165,824 B
  unsigned short* xh    = (unsigned short*)(ws + 100663296L);    // 25,165,824 B
  unsigned short* Vt    = (unsigned short*)(ws + 125829120L);    // 25,165,824 B
  unsigned short* WqkvT = (unsigned short*)(ws + 150994944L);    //  3,538,944 B
  unsigned short* WoutT = (unsigned short*)(ws + 154533888L);    //  1,179,648 B
  // total: 155,713,536 B

  k_prep_all<<<7296, 256, 0, stream>>>(x, Wqkv, Wout, xh, WqkvT, WoutT);
  gemm128<1><<<2304, 256, 0, stream>>>(xh, WqkvT, bqkv, (void*)qkvb, Vt, 768, 2304);
  attn_fused<<<768, 512, 0, stream>>>(qkvb, Vt, Ofp);
  gemm128<3><<<768, 256, 0, stream>>>(Ofp, WoutT, bout, d_out, nullptr, 768, 768);
}

// Round 17
// 175.115 us; speedup vs baseline: 1.0131x; 1.0131x over previous
//
#include <hip/hip_runtime.h>
#include <hip/hip_bf16.h>

// Problem constants
#define B_   16
#define N_   1024
#define C_   768
#define H_   12
#define HD_  64
#define M_   16384   // B*N tokens
#define N1_  2304    // 3*C
#define NEG_BIG (-1e30f)
#define LOG2E 1.4426950408889634f

typedef __attribute__((ext_vector_type(8))) _Float16 f16x8;  // 8 fp16 = 4 VGPR
typedef __attribute__((ext_vector_type(2))) _Float16 f16x2;  // packed pair
typedef __attribute__((ext_vector_type(4))) float f32x4;
typedef __attribute__((ext_vector_type(16))) float f32x16;

// ---- fp16 helpers ----
__device__ __forceinline__ unsigned short f2h(float f) {   // RNE
  _Float16 h = (_Float16)f;
  union { _Float16 h; unsigned short u; } c; c.h = h; return c.u;
}
__device__ __forceinline__ unsigned int cvtpk_f16(float a, float b) {  // RTZ pack
  unsigned int r;
  asm("v_cvt_pkrtz_f16_f32 %0, %1, %2" : "=v"(r) : "v"(a), "v"(b));
  return r;
}
__device__ __forceinline__ float exp2_asm(float x) {
  float r;
  asm("v_exp_f32 %0, %1" : "=v"(r) : "v"(x));
  return r;
}

__device__ __forceinline__ void gload_lds16(const void* g, void* l) {
  __builtin_amdgcn_global_load_lds(
      (const __attribute__((address_space(1))) void*)g,
      (__attribute__((address_space(3))) void*)l, 16, 0, 0);
}

typedef __attribute__((ext_vector_type(8))) short u16x8;

// =====================================================================
// Fused prep: blocks [0,6144) cvt x; [6144,7008) WqkvT; [7008,7296) WoutT
// =====================================================================
__global__ __launch_bounds__(256)
void k_prep_all(const float* __restrict__ x, const float* __restrict__ Wqkv,
                const float* __restrict__ Wout,
                unsigned short* __restrict__ xh,
                unsigned short* __restrict__ WqkvT,
                unsigned short* __restrict__ WoutT) {
  int bid = blockIdx.x;
  if (bid < 6144) {
    long i = ((long)bid * 256 + threadIdx.x) * 8;
    float4 a = *(const float4*)(x + i);
    float4 b = *(const float4*)(x + i + 4);
    u16x8 v;
    v[0] = (short)f2h(a.x); v[1] = (short)f2h(a.y);
    v[2] = (short)f2h(a.z); v[3] = (short)f2h(a.w);
    v[4] = (short)f2h(b.x); v[5] = (short)f2h(b.y);
    v[6] = (short)f2h(b.z); v[7] = (short)f2h(b.w);
    *(u16x8*)(xh + i) = v;
  } else if (bid < 7008) {
    int tid = (bid - 6144) * 256 + threadIdx.x;   // 96*2304 threads
    int n  = tid % N1_;
    int kc = tid / N1_;                            // 0..95
    u16x8 v;
#pragma unroll
    for (int j = 0; j < 8; ++j)
      v[j] = (short)f2h(Wqkv[(long)(kc * 8 + j) * N1_ + n]);
    *(u16x8*)(WqkvT + (long)n * C_ + kc * 8) = v;
  } else {
    int tid = (bid - 7008) * 256 + threadIdx.x;   // 96*768 threads
    int n  = tid % C_;
    int kc = tid / C_;                             // 0..95
    u16x8 v;
#pragma unroll
    for (int j = 0; j < 8; ++j)
      v[j] = (short)f2h(Wout[(long)(kc * 8 + j) * C_ + n]);
    *(u16x8*)(WoutT + (long)n * C_ + kc * 8) = v;
  }
}

// =====================================================================
// 128x128 GEMM (m97 2-barrier structure, fp16): C = A * Bt^T + bias
// STAGE 1: fp16 out. Q/K col-blocks -> qkvb; V col-blocks (n0>=1536)
// transposed directly into Vt [bh][64 d][1024 n]. STAGE 3: fp32 direct.
// =====================================================================
template <int STAGE>
__global__ __launch_bounds__(256, 4)
void gemm128(const unsigned short* __restrict__ A,
             const unsigned short* __restrict__ Bt,
             const float* __restrict__ bias,
             void* __restrict__ out, unsigned short* __restrict__ Vt,
             int Kdim, int Ndim) {
  __shared__ unsigned char lds[32768];   // A tile 16K | B tile 16K
  const int t = threadIdx.x;
  const int l = t & 63, w = t >> 6;
  const int g = l >> 4, lr = l & 15;
  const int NB = Ndim >> 7;
  const int wgid = (blockIdx.x & 7) * (gridDim.x >> 3) + (blockIdx.x >> 3);
  const int mb = wgid / NB, nb = wgid % NB;
  const long m0 = (long)mb << 7, n0 = (long)nb << 7;
  const int wm = w >> 1, wn = w & 1;

  f32x4 acc[4][4];
  const f32x4 zz = {0.f, 0.f, 0.f, 0.f};
#pragma unroll
  for (int i = 0; i < 4; ++i)
#pragma unroll
    for (int j = 0; j < 4; ++j) acc[i][j] = zz;

  int srow[4], sx[4];
#pragma unroll
  for (int i = 0; i < 4; ++i) {
    int s = i * 4096 + t * 16;
    int row = s >> 7;
    srow[i] = row;
    sx[i] = (s & 127) ^ ((row & 7) << 4);
  }
  const char* Ab = (const char*)A;
  const char* Bb = (const char*)Bt;
  const long K2 = (long)Kdim * 2;
  const int wbase = (t & 192) * 16;   // wave-uniform LDS base (w*1024)

  for (int kt = 0; kt < Kdim; kt += 64) {
#pragma unroll
    for (int i = 0; i < 4; ++i) {
      const char* src = Ab + (m0 + srow[i]) * K2 + kt * 2 + sx[i];
      gload_lds16(src, (void*)(lds + i * 4096 + wbase));
    }
#pragma unroll
    for (int i = 0; i < 4; ++i) {
      const char* src = Bb + (n0 + srow[i]) * K2 + kt * 2 + sx[i];
      gload_lds16(src, (void*)(lds + 16384 + i * 4096 + wbase));
    }
    __syncthreads();
#pragma unroll
    for (int ks = 0; ks < 2; ++ks) {
      f16x8 af[4], bfr[4];
#pragma unroll
      for (int mi = 0; mi < 4; ++mi) {
        int row = wm * 64 + mi * 16 + lr;
        int off = row * 128 + ((ks * 64 + g * 16) ^ ((row & 7) << 4));
        af[mi] = *(const f16x8*)(lds + off);
      }
#pragma unroll
      for (int ni = 0; ni < 4; ++ni) {
        int row = wn * 64 + ni * 16 + lr;
        int off = 16384 + row * 128 + ((ks * 64 + g * 16) ^ ((row & 7) << 4));
        bfr[ni] = *(const f16x8*)(lds + off);
      }
#pragma unroll
      for (int mi = 0; mi < 4; ++mi)
#pragma unroll
        for (int ni = 0; ni < 4; ++ni)
          acc[mi][ni] = __builtin_amdgcn_mfma_f32_16x16x32_f16(
              af[mi], bfr[ni], acc[mi][ni], 0, 0, 0);
    }
    __syncthreads();
  }

  // ---- epilogue ----
  if (STAGE == 1 && n0 >= 1536) {
    // V path: stage C-tile COL-MAJOR (lt[col][row^s]) then write Vt rows
    unsigned short* lt = (unsigned short*)lds;
#pragma unroll
    for (int ni = 0; ni < 4; ++ni) {
      int col = wn * 64 + ni * 16 + lr;
      int s = (col & 15) << 3;
      float bv = bias[(int)n0 + col];
#pragma unroll
      for (int mi = 0; mi < 4; ++mi) {
        int rowb = wm * 64 + mi * 16 + g * 4;
        unsigned d0 = cvtpk_f16(acc[mi][ni][0] + bv, acc[mi][ni][1] + bv);
        unsigned d1 = cvtpk_f16(acc[mi][ni][2] + bv, acc[mi][ni][3] + bv);
        unsigned long long dd = (unsigned long long)d0 |
                                ((unsigned long long)d1 << 32);
        *(unsigned long long*)(lt + col * 128 + (rowb ^ s)) = dd;
      }
    }
    __syncthreads();
    const int b_  = (int)(m0 >> 10);
    const int nof = (int)(m0 & 1023);
    const int h0  = ((int)n0 - 1536) >> 6;
#pragma unroll
    for (int it = 0; it < 8; ++it) {
      int col  = it * 16 + (t >> 4);
      int tokc = (t & 15) * 8;
      int s = (col & 15) << 3;
      u16x8 v = *(const u16x8*)(lt + col * 128 + (tokc ^ s));
      int bh = b_ * H_ + h0 + (col >> 6);
      int d  = col & 63;
      *(u16x8*)(Vt + ((long)bh * HD_ + d) * N_ + nof + tokc) = v;
    }
  } else if (STAGE == 1) {
    float sc = (n0 < 768) ? 0.125f * LOG2E : 1.0f;  // Q pre-scale (exp2 dom)
    unsigned short* cl = (unsigned short*)lds;
#pragma unroll
    for (int ni = 0; ni < 4; ++ni) {
      int col = wn * 64 + ni * 16 + lr;
      float bv = bias[(int)n0 + col];
#pragma unroll
      for (int mi = 0; mi < 4; ++mi)
#pragma unroll
        for (int r = 0; r < 4; ++r) {
          int row = wm * 64 + mi * 16 + g * 4 + r;
          cl[row * 128 + col] = f2h((acc[mi][ni][r] + bv) * sc);
        }
    }
    __syncthreads();
    unsigned short* o = (unsigned short*)out;
#pragma unroll
    for (int it = 0; it < 8; ++it) {
      int idx = it * 2048 + t * 8;         // shorts
      int row = idx >> 7;
      int col = idx & 127;
      *(u16x8*)(o + (m0 + row) * N1_ + n0 + col) = *(const u16x8*)(cl + idx);
    }
  } else {
    float* o = (float*)out;
#pragma unroll
    for (int ni = 0; ni < 4; ++ni) {
      int col = (int)n0 + wn * 64 + ni * 16 + lr;
      float bv = bias[col];
#pragma unroll
      for (int mi = 0; mi < 4; ++mi)
#pragma unroll
        for (int r = 0; r < 4; ++r) {
          long rowm = m0 + wm * 64 + mi * 16 + g * 4 + r;
          o[rowm * C_ + col] = acc[mi][ni][r] + bv;
        }
    }
  }
}

// =====================================================================
// Fused flash attention, 32x32x16 fp16 MFMA, fully-transposed form.
// r14 structure (tri-buffered K/V, 1 barrier/tile) with the row-sum
// computed by a packed-fp16 tree over the pk words (15 v_pk_add_f16
// vs 31 f32 adds; P <= 2^8 so no overflow; normalizes by the actual
// fp16-rounded P fed to PV). setprio reverted (measured neutral).
// 512 threads / 8 waves / 256 q per block; grid 768 = 3 blocks/CU.
// =====================================================================
__global__ __launch_bounds__(512, 2)
void attn_fused(const unsigned short* __restrict__ qkvb,
                const unsigned short* __restrict__ Vt,
                unsigned short* __restrict__ Ofp) {
  __shared__ unsigned char lds[49152];  // 3 x (K 8K | V 8K)
  const int t = threadIdx.x, l = t & 63, w = t >> 6;   // 8 waves
  const int q32 = l & 31;
  const int hi = l >> 5;
  const int hi16 = hi * 16;
  const int wid = (blockIdx.x & 7) * 96 + (blockIdx.x >> 3);  // XCD-chunked
  const int bh = wid >> 2, qb = wid & 3;
  const int b = bh / H_, h = bh % H_;
  const long tok0 = (long)b * N_;
  const int q0 = qb * 256 + w * 32;
  const long mytok = tok0 + q0 + q32;

  // Q B-fragments (pre-scaled by 0.125*log2e in stage-1)
  f16x8 qa[4];
#pragma unroll
  for (int cs = 0; cs < 4; ++cs)
    qa[cs] = *(const f16x8*)(qkvb + mytok * N1_ + h * HD_ + cs * 16 + hi * 8);

  const f32x16 zz16 = {0.f};
  f32x16 o0 = zz16, o1 = zz16;   // O^T: d 0..31 / 32..63 for lane's q
  float mrun = NEG_BIG, lrun = 0.f;

  const int row0 = q32, row1 = 32 + q32;
  const int swz0 = (q32 & 7) << 4;    // period-8 / 16B XOR

  // staging: 512 threads cover one 16KB K/V tile pair per issue;
  // row = t>>3 (0..63), col = (t&7)*16, source pre-swizzled
  const int srowk = t >> 3;
  const int sxs = ((t & 7) * 16) ^ (((t >> 3) & 7) << 4);
  const int wbase = (t & 448) * 16;   // w * 1024
  const char* Vg = (const char*)(Vt + (long)bh * HD_ * N_);
  const char* Kg = (const char*)qkvb + ((tok0)*N1_ + C_ + h * HD_) * 2;

#define STAGE_KV(kv0, buf)                                                  \
  {                                                                         \
    gload_lds16(Kg + ((long)((kv0) + srowk) * N1_) * 2 + sxs,               \
                (void*)((buf) + wbase));                                    \
    gload_lds16(Vg + ((long)srowk * N_ + (kv0)) * 2 + sxs,                  \
                (void*)((buf) + 8192 + wbase));                             \
  }

  STAGE_KV(0, lds);            // tile 0 -> buf 0
  STAGE_KV(64, lds + 16384);   // tile 1 -> buf 1

  int cur = 0, nx2 = 2;        // rolling buffer indices: tt%3, (tt+2)%3
  for (int tt = 0; tt < 16; ++tt) {
    unsigned char* curb = lds + cur * 16384;
    if (tt < 15) {
      asm volatile("s_waitcnt vmcnt(2)" ::: "memory");   // tile-tt data landed
    } else {
      asm volatile("s_waitcnt vmcnt(0)" ::: "memory");
    }
    __builtin_amdgcn_s_barrier();          // all waves now inside tile tt
    __builtin_amdgcn_sched_barrier(0);
    if (tt + 2 < 16) {
      STAGE_KV((tt + 2) * 64, lds + nx2 * 16384);  // hides under compute
    }

    // ---- S^T = mfma(K_A, Q_B) ----
    f32x16 sa0 = zz16, sa1 = zz16;
#pragma unroll
    for (int cs = 0; cs < 4; ++cs) {
      f16x8 kf0 = *(const f16x8*)(curb + row0 * 128 + ((cs * 32 + hi16) ^ swz0));
      f16x8 kf1 = *(const f16x8*)(curb + row1 * 128 + ((cs * 32 + hi16) ^ swz0));
      sa0 = __builtin_amdgcn_mfma_f32_32x32x16_f16(kf0, qa[cs], sa0, 0, 0, 0);
      sa1 = __builtin_amdgcn_mfma_f32_32x32x16_f16(kf1, qa[cs], sa1, 0, 0, 0);
    }

    // ---- in-lane online softmax (log2 domain), max3-fused tree ----
    float tm[11];
#pragma unroll
    for (int i = 0; i < 5; ++i)
      tm[i] = fmaxf(fmaxf(sa0[3 * i], sa0[3 * i + 1]), sa0[3 * i + 2]);
    tm[5] = fmaxf(sa0[15], sa1[0]);
#pragma unroll
    for (int i = 0; i < 5; ++i)
      tm[6 + i] = fmaxf(fmaxf(sa1[3 * i + 1], sa1[3 * i + 2]), sa1[3 * i + 3]);
    float u0 = fmaxf(fmaxf(tm[0], tm[1]), tm[2]);
    float u1 = fmaxf(fmaxf(tm[3], tm[4]), tm[5]);
    float u2 = fmaxf(fmaxf(tm[6], tm[7]), tm[8]);
    float u3 = fmaxf(fmaxf(tm[9], tm[10]), u0);
    float mx = fmaxf(fmaxf(u1, u2), u3);
    mx = fmaxf(mx, __shfl_xor(mx, 32));
    if (!__all(mx <= mrun + 8.f)) {           // defer-max: P <= 2^8
      float mn = fmaxf(mrun, mx);
      float al = exp2_asm(mrun - mn);
      mrun = mn;
      lrun *= al;
      o0 *= al;
      o1 *= al;
    }
    float p0a[16], p1a[16];
#pragma unroll
    for (int i = 0; i < 16; ++i) p0a[i] = exp2_asm(sa0[i] - mrun);
#pragma unroll
    for (int i = 0; i < 16; ++i) p1a[i] = exp2_asm(sa1[i] - mrun);
    unsigned pk[2][4][2];
#pragma unroll
    for (int g = 0; g < 4; ++g) {
      pk[0][g][0] = cvtpk_f16(p0a[4 * g + 0], p0a[4 * g + 1]);
      pk[0][g][1] = cvtpk_f16(p0a[4 * g + 2], p0a[4 * g + 3]);
      pk[1][g][0] = cvtpk_f16(p1a[4 * g + 0], p1a[4 * g + 1]);
      pk[1][g][1] = cvtpk_f16(p1a[4 * g + 2], p1a[4 * g + 3]);
    }
    // ---- row-sum via packed-fp16 tree over pk (15 v_pk_add_f16) ----
    {
      union U { unsigned u; f16x2 h; };
      f16x2 s0, s1, s2, s3, s4, s5, s6, s7;
      { U a, c; a.u = pk[0][0][0]; c.u = pk[0][0][1]; s0 = a.h + c.h; }
      { U a, c; a.u = pk[0][1][0]; c.u = pk[0][1][1]; s1 = a.h + c.h; }
      { U a, c; a.u = pk[0][2][0]; c.u = pk[0][2][1]; s2 = a.h + c.h; }
      { U a, c; a.u = pk[0][3][0]; c.u = pk[0][3][1]; s3 = a.h + c.h; }
      { U a, c; a.u = pk[1][0][0]; c.u = pk[1][0][1]; s4 = a.h + c.h; }
      { U a, c; a.u = pk[1][1][0]; c.u = pk[1][1][1]; s5 = a.h + c.h; }
      { U a, c; a.u = pk[1][2][0]; c.u = pk[1][2][1]; s6 = a.h + c.h; }
      { U a, c; a.u = pk[1][3][0]; c.u = pk[1][3][1]; s7 = a.h + c.h; }
      s0 = s0 + s1; s2 = s2 + s3; s4 = s4 + s5; s6 = s6 + s7;
      s0 = s0 + s2; s4 = s4 + s6;
      s0 = s0 + s4;
      float rs = (float)s0[0] + (float)s0[1];
      rs += __shfl_xor(rs, 32);
      lrun += rs;
    }

    // ---- P^T -> B-operand fragments via permlane32_swap ----
    f16x8 pb[4];
#pragma unroll
    for (int tk = 0; tk < 2; ++tk)
#pragma unroll
      for (int par = 0; par < 2; ++par) {
        unsigned a0 = pk[tk][2 * par][0], b0 = pk[tk][2 * par + 1][0];
        unsigned a1 = pk[tk][2 * par][1], b1 = pk[tk][2 * par + 1][1];
        asm("v_permlane32_swap_b32 %0, %1" : "+v"(a0), "+v"(b0));
        asm("v_permlane32_swap_b32 %0, %1" : "+v"(a1), "+v"(b1));
        union { unsigned u[4]; f16x8 v; } pw;
        pw.u[0] = a0; pw.u[1] = a1; pw.u[2] = b0; pw.u[3] = b1;
        pb[2 * tk + par] = pw.v;
      }

    // ---- O^T += mfma(V^T_A, P_B) ----
#pragma unroll
    for (int kb = 0; kb < 4; ++kb) {
      f16x8 vf0 = *(const f16x8*)(curb + 8192 + row0 * 128 + ((kb * 32 + hi16) ^ swz0));
      f16x8 vf1 = *(const f16x8*)(curb + 8192 + row1 * 128 + ((kb * 32 + hi16) ^ swz0));
      o0 = __builtin_amdgcn_mfma_f32_32x32x16_f16(vf0, pb[kb], o0, 0, 0, 0);
      o1 = __builtin_amdgcn_mfma_f32_32x32x16_f16(vf1, pb[kb], o1, 0, 0, 0);
    }
    // rotate buffer indices (no second barrier: tri-buffer makes it safe)
    cur = (cur == 2) ? 0 : cur + 1;
    nx2 = (nx2 == 2) ? 0 : nx2 + 1;
  }
#undef STAGE_KV

  // ---- epilogue: normalize, fp16 pack, merged 8B stores ----
  float inv = 1.0f / lrun;
  unsigned short* obase = Ofp + mytok * C_ + h * HD_;
#pragma unroll
  for (int dt = 0; dt < 2; ++dt) {
#pragma unroll
    for (int j = 0; j < 4; ++j) {
      int r = 4 * j;
      const f32x16& oo = dt ? o1 : o0;
      unsigned hw0 = cvtpk_f16(oo[r] * inv, oo[r + 1] * inv);
      unsigned hw1 = cvtpk_f16(oo[r + 2] * inv, oo[r + 3] * inv);
      unsigned long long dd = (unsigned long long)hw0 |
                              ((unsigned long long)hw1 << 32);
      int d = dt * 32 + 8 * j + 4 * hi;
      *(unsigned long long*)(obase + d) = dd;
    }
  }
}

// =====================================================================
extern "C" void kernel_launch(void* const* d_in, const int* in_sizes, int n_in,
                              void* d_out, int out_size, void* d_ws, size_t ws_size,
                              hipStream_t stream) {
  const float* x    = (const float*)d_in[0];
  const float* Wqkv = (const float*)d_in[1];
  const float* bqkv = (const float*)d_in[2];
  const float* Wout = (const float*)d_in[3];
  const float* bout = (const float*)d_in[4];

  char* ws = (char*)d_ws;
  unsigned short* qkvb  = (unsigned short*)(ws);                 // 75,497,472 B
  unsigned short* Ofp   = (unsigned short*)(ws + 75497472L);     // 25,165,824 B
  unsigned short* xh    = (unsigned short*)(ws + 100663296L);    // 25,165,824 B
  unsigned short* Vt    = (unsigned short*)(ws + 125829120L);    // 25,165,824 B
  unsigned short* WqkvT = (unsigned short*)(ws + 150994944L);    //  3,538,944 B
  unsigned short* WoutT = (unsigned short*)(ws + 154533888L);    //  1,179,648 B
  // total: 155,713,536 B

  k_prep_all<<<7296, 256, 0, stream>>>(x, Wqkv, Wout, xh, WqkvT, WoutT);
  gemm128<1><<<2304, 256, 0, stream>>>(xh, WqkvT, bqkv, (void*)qkvb, Vt, 768, 2304);
  attn_fused<<<768, 512, 0, stream>>>(qkvb, Vt, Ofp);
  gemm128<3><<<768, 256, 0, stream>>>(Ofp, WoutT, bout, d_out, nullptr, 768, 768);
}